// Round 11
// baseline (493.272 us; speedup 1.0000x reference)
//
#include <hip/hip_runtime.h>
#include <cstdint>
#include <cstddef>

// PiFormerBlock, MFMA fp16 version, round 11.
//   x = x + linattn(LN1(x)) @ wo ;  x = x + gelu_lut(LN2(x) @ w1) @ w2
// Round-11: best-of-rounds-8/9 combo + L2-aware band orientation.
//  - BK=64 kernels (qkv, w1): (r&7) LDS swizzle (0 conflicts, r5-r8).
//  - BK=128 kernels (wo, w2): frow=(r^(r>>3))&7 swizzle (r9: fixed the 2^23
//    conflict cycles that (r&7) caused at 256B row stride).
//  - XCD band orientation per GEMM: m-band (XCD owns m rows, walks n) when B
//    fits L2 (wo 2MB, w2-ish); n-band (XCD owns n cols, walks m) when B is
//    big but a band of it fits (w1 8MB -> 1MB/XCD, qkv 6MB -> 768KB/XCD).
//    r10 counters: w1 under m-band refetched B per m-block -> FETCH 164MB vs
//    24MB ideal.
//  - No double-buffer (r10: __syncthreads drains the prefetch too; m99 redux).
//
// ws layout (bytes):
//   0      xn    [8192x1024] fp16 (16MB)  (reused as attn out)
//   32MB   phiq  fp16 (16MB) \
//   48MB   phik  fp16 (16MB)  >-- contiguous qkv slab; later overlaid by
//   64MB   vbuf  fp16 (16MB) /    ffn fp16 [8192x4096] (64MB @ 32MB)
//   96MB   w1T   fp16 (8MB) | 104MB w2T fp16 (8MB) | 128MB woT fp16 (2MB)
// d_out scratch (dead before wo-GEMM writes it):
//   0MB wqkvT (6MB) | 6MB kv partials (17.04MB) | 24MB kv (1MB) | 25MB z

#define D_MODEL 1024
#define SEQ     2048
#define BATCH   4
#define NTOK    8192
#define NHEADS  16
#define DH      64
#define DFF     4096
#define KVCH    16
#define CHROWS  (SEQ / KVCH)
#define PSTRIDE 4160

typedef _Float16 half8 __attribute__((ext_vector_type(8)));
typedef float f32x4 __attribute__((ext_vector_type(4)));

__device__ __forceinline__ unsigned short f2h(float x) {
  _Float16 h = (_Float16)x;
  union { _Float16 h; unsigned short u; } c; c.h = h; return c.u;
}
__device__ __forceinline__ float h2f(unsigned short u) {
  union { unsigned short u; _Float16 h; } c; c.u = u; return (float)c.h;
}

__device__ __forceinline__ float phi_act(float x) {
  return x > 0.f ? x + 1.f : expf(x);
}

__device__ __forceinline__ float gelu_exact(float v) {
  float c = 0.7978845608028654f;
  float t = tanhf(c * (v + 0.044715f * v * v * v));
  return 0.5f * v * (1.f + t);
}

// per-BK row->segment swizzle (both measured-optimal):
//   BK=64 : r&7          (0 conflicts, rounds 5-8)
//   BK=128: (r^(r>>3))&7 (round 9 fixed the 4cyc/b128 penalty of r&7)
template <int BK>
__device__ __forceinline__ int fr(int r) {
  return (BK == 128) ? ((r ^ (r >> 3)) & 7) : (r & 7);
}

__device__ __forceinline__ void gl_lds16(const void* g, void* l) {
  __builtin_amdgcn_global_load_lds(
      (const __attribute__((address_space(1))) unsigned int*)g,
      (__attribute__((address_space(3))) unsigned int*)l, 16, 0, 0);
}

// ------- batched transpose-convert: 4x [1024,1024] fp32 -> fp16 [N,K]^T -----
__global__ __launch_bounds__(256) void convT4(const float* __restrict__ W0,
                                              const float* __restrict__ W1,
                                              const float* __restrict__ W2,
                                              const float* __restrict__ W3,
                                              unsigned short* __restrict__ D0,
                                              unsigned short* __restrict__ D3) {
  __shared__ float tile[64][65];
  int zz = blockIdx.z;
  const float* W = zz == 0 ? W0 : zz == 1 ? W1 : zz == 2 ? W2 : W3;
  unsigned short* WT = zz < 3 ? (D0 + (size_t)zz * D_MODEL * D_MODEL) : D3;
  int kb = blockIdx.y << 6, nb = blockIdx.x << 6;
  int t = threadIdx.x;
  int rr = t >> 4, cc = (t & 15) << 2;
#pragma unroll
  for (int i = 0; i < 4; ++i) {
    int r = rr + (i << 4);
    float4 v = *(const float4*)(W + (size_t)(kb + r) * D_MODEL + nb + cc);
    tile[r][cc] = v.x; tile[r][cc + 1] = v.y; tile[r][cc + 2] = v.z; tile[r][cc + 3] = v.w;
  }
  __syncthreads();
#pragma unroll
  for (int i = 0; i < 4; ++i) {
    int n = rr + (i << 4);
    ushort4 o;
    o.x = f2h(tile[cc + 0][n]); o.y = f2h(tile[cc + 1][n]);
    o.z = f2h(tile[cc + 2][n]); o.w = f2h(tile[cc + 3][n]);
    *(ushort4*)(WT + (size_t)(nb + n) * D_MODEL + kb + cc) = o;
  }
}

// ---------------- transpose-convert: W fp32 [K,N] -> WT fp16 [N,K] ----------
__global__ __launch_bounds__(256) void convT(const float* __restrict__ W,
                                             unsigned short* __restrict__ WT,
                                             int K, int N) {
  __shared__ float tile[64][65];
  int kb = blockIdx.y << 6, nb = blockIdx.x << 6;
  int t = threadIdx.x;
  int rr = t >> 4, cc = (t & 15) << 2;
#pragma unroll
  for (int i = 0; i < 4; ++i) {
    int r = rr + (i << 4);
    float4 v = *(const float4*)(W + (size_t)(kb + r) * N + nb + cc);
    tile[r][cc] = v.x; tile[r][cc + 1] = v.y; tile[r][cc + 2] = v.z; tile[r][cc + 3] = v.w;
  }
  __syncthreads();
#pragma unroll
  for (int i = 0; i < 4; ++i) {
    int n = rr + (i << 4);
    ushort4 o;
    o.x = f2h(tile[cc + 0][n]); o.y = f2h(tile[cc + 1][n]);
    o.z = f2h(tile[cc + 2][n]); o.w = f2h(tile[cc + 3][n]);
    *(ushort4*)(WT + (size_t)(nb + n) * K + kb + cc) = o;
  }
}

// ---------------- LayerNorm -> fp16 ----------------------------------------
__global__ __launch_bounds__(256) void ln_kernel(const float* __restrict__ X,
                                                 const float* __restrict__ g,
                                                 const float* __restrict__ b,
                                                 unsigned short* __restrict__ Y) {
  int tok = blockIdx.x;
  int t = threadIdx.x;
  const float4* xr = (const float4*)(X + (size_t)tok * D_MODEL);
  float4 v = xr[t];
  float s  = v.x + v.y + v.z + v.w;
  float s2 = v.x * v.x + v.y * v.y + v.z * v.z + v.w * v.w;
#pragma unroll
  for (int o = 32; o > 0; o >>= 1) {
    s  += __shfl_down(s, o);
    s2 += __shfl_down(s2, o);
  }
  __shared__ float red[8];
  __shared__ float mu_s, rs_s;
  int wid = t >> 6;
  if ((t & 63) == 0) { red[wid] = s; red[wid + 4] = s2; }
  __syncthreads();
  if (t == 0) {
    float ts  = red[0] + red[1] + red[2] + red[3];
    float ts2 = red[4] + red[5] + red[6] + red[7];
    float mu  = ts * (1.f / D_MODEL);
    float var = ts2 * (1.f / D_MODEL) - mu * mu;
    mu_s = mu;
    rs_s = rsqrtf(var + 1e-5f);
  }
  __syncthreads();
  float mu = mu_s, rs = rs_s;
  float4 gv = ((const float4*)g)[t];
  float4 bv = ((const float4*)b)[t];
  ushort4 hv;
  hv.x = f2h((v.x - mu) * rs * gv.x + bv.x);
  hv.y = f2h((v.y - mu) * rs * gv.y + bv.y);
  hv.z = f2h((v.z - mu) * rs * gv.z + bv.z);
  hv.w = f2h((v.w - mu) * rs * gv.w + bv.w);
  ((ushort4*)(Y + (size_t)tok * D_MODEL))[t] = hv;
}

// ---------------- MFMA GEMM: C[M,N] = A[M,K] @ BT[N,K]^T (fp16 in) ---------
// EP: 0 fp32 | 2 +R fp32 | 3 gelu-LUT fp16 | 4 fused qkv (phi on q/k) fp16
// BK: K-chunk per barrier. BAND: 0 = XCD owns m-band walks n (B small/L2-fit)
//                                1 = XCD owns n-band walks m (B large)
template <int EP, int BK, int BAND>
__global__ __launch_bounds__(256, (BK == 64) ? 4 : 2) void mfma_gemm(
    const unsigned short* __restrict__ A,
    const unsigned short* __restrict__ BT,
    void* Cv, const float* R, int N, int K) {
  constexpr int SEGS = BK / 8;     // 16B segments per row
  constexpr int RPC  = 64 / SEGS;  // rows covered by one gl_lds16 call
  constexpr int NJ   = 32 / RPC;   // calls per wave per tile (32 rows/wave)
  __shared__ unsigned short smem[2 * 128 * BK];
  __shared__ float gtab[EP == 3 ? 256 : 1];
  unsigned short* sA = smem;
  unsigned short* sB = smem + 128 * BK;

  int t = threadIdx.x;
  if (EP == 3) gtab[t & 255] = gelu_exact((float)((t & 255) - 128) * 0.1f);

  // XCD-aware swizzle (8 XCDs, round-robin on linear block id).
  int bm, bn;
  {
    int L = blockIdx.y * gridDim.x + blockIdx.x;
    if (BAND == 0 && (gridDim.y & 7) == 0) {
      int xcd = L & 7, wi = L >> 3;
      int mPerX = gridDim.y >> 3;
      bm = xcd * mPerX + wi / gridDim.x;   // XCD owns m band
      bn = wi % gridDim.x;                 // n fastest (A-tile L2 reuse)
    } else if (BAND == 1 && (gridDim.x & 7) == 0) {
      int xcd = L & 7, wi = L >> 3;
      int nPerX = gridDim.x >> 3;
      bn = xcd * nPerX + wi / gridDim.y;   // XCD owns n band (B L2-resident)
      bm = wi % gridDim.y;                 // m fastest (A streams once)
    } else {
      bn = blockIdx.x; bm = blockIdx.y;
    }
  }

  int w = t >> 6, l = t & 63;
  int lrow = l / SEGS;             // row within call group
  int lseg = l & (SEGS - 1);       // 16B segment within row
  int m0 = bm << 7;
  int n0 = bn << 7;
  size_t strideB = (size_t)K * 2;

  const char* gA[NJ]; const char* gB[NJ];
  int ldsOff[NJ];
#pragma unroll
  for (int j = 0; j < NJ; ++j) {
    int row = (w << 5) + j * RPC + lrow;
    int gso = (lseg ^ fr<BK>(row)) << 4;   // swizzled segment offset (bytes)
    gA[j] = (const char*)A + (size_t)(m0 + row) * strideB + gso;
    gB[j] = (const char*)BT + (size_t)(n0 + row) * strideB + gso;
    ldsOff[j] = ((w << 5) + j * RPC) * BK;  // shorts
  }

  int wm = w >> 1, wn = w & 1;
  int m16 = l & 15, qd = l >> 4;

  f32x4 acc[4][4];
#pragma unroll
  for (int i = 0; i < 4; ++i)
#pragma unroll
    for (int j = 0; j < 4; ++j) acc[i][j] = (f32x4){0.f, 0.f, 0.f, 0.f};

  for (int k0 = 0; k0 < K; k0 += BK) {
    size_t kb = (size_t)k0 * 2;
#pragma unroll
    for (int j = 0; j < NJ; ++j) {
      gl_lds16(gA[j] + kb, sA + ldsOff[j]);
      gl_lds16(gB[j] + kb, sB + ldsOff[j]);
    }
    __syncthreads();
#pragma unroll
    for (int kk = 0; kk < BK / 32; ++kk) {
      int ksb = (kk << 2) + qd;
      half8 af[4], bf[4];
#pragma unroll
      for (int mt = 0; mt < 4; ++mt) {
        int r = (wm << 6) + (mt << 4) + m16;
        int slot = ksb ^ fr<BK>(r);
        af[mt] = *(const half8*)(sA + r * BK + (slot << 3));
      }
#pragma unroll
      for (int nt = 0; nt < 4; ++nt) {
        int r = (wn << 6) + (nt << 4) + m16;
        int slot = ksb ^ fr<BK>(r);
        bf[nt] = *(const half8*)(sB + r * BK + (slot << 3));
      }
#pragma unroll
      for (int mt = 0; mt < 4; ++mt)
#pragma unroll
        for (int nt = 0; nt < 4; ++nt)
          acc[mt][nt] = __builtin_amdgcn_mfma_f32_16x16x32_f16(af[mt], bf[nt], acc[mt][nt], 0, 0, 0);
    }
    __syncthreads();
  }

  // EP=4: destination slab by column block (n0 is 128-aligned, slabs 1024-wide)
  int sel = n0 >> 10;                       // 0=q 1=k 2=v
  size_t slab = (size_t)sel * ((size_t)NTOK * D_MODEL);
  int colL = (n0 & 1023) + (wn << 6) + m16; // local col within slab

  int colBase = n0 + (wn << 6) + m16;
#pragma unroll
  for (int mt = 0; mt < 4; ++mt) {
    int rBase = m0 + (wm << 6) + (mt << 4) + (qd << 2);
#pragma unroll
    for (int nt = 0; nt < 4; ++nt) {
      int col = colBase + (nt << 4);
#pragma unroll
      for (int i = 0; i < 4; ++i) {
        float v = acc[mt][nt][i];
        if (EP == 4) {
          if (sel < 2) v = phi_act(v);
          size_t idx = slab + (size_t)(rBase + i) * D_MODEL + colL + (nt << 4);
          ((unsigned short*)Cv)[idx] = f2h(v);
        } else {
          size_t idx = (size_t)(rBase + i) * N + col;
          if (EP == 2)      ((float*)Cv)[idx] = R[idx] + v;
          else if (EP == 3) {
            float r = rintf(v / 0.1f);
            int iq = (int)r + 128;
            iq = iq < 0 ? 0 : (iq > 255 ? 255 : iq);
            ((unsigned short*)Cv)[idx] = f2h(gtab[iq]);
          } else          ((float*)Cv)[idx] = v;
        }
      }
    }
  }
}

// ---------------- stage 1: partial kv/z over an S-chunk (fp16 in) ----------
__global__ __launch_bounds__(256) void kvz_partial(const unsigned short* __restrict__ PK,
                                                   const unsigned short* __restrict__ V,
                                                   float* __restrict__ P) {
  int c = blockIdx.x, bh = blockIdx.y;
  int b = bh >> 4, h = bh & 15;
  __shared__ float pk[8][64];
  __shared__ float vv[8][64];
  int t = threadIdx.x;
  const size_t base = ((size_t)b * SEQ + (size_t)c * CHROWS) * D_MODEL + h * DH;
  int u = t & 127;
  int lrow = u >> 4;
  int lcol = (u & 15) << 2;
  bool isV = (t >= 128);
  const unsigned short* src = isV ? V : PK;
  int dkb = (t >> 4) << 2;
  int deb = (t & 15) << 2;
  float acc[4][4] = {};
  float zacc = 0.f;
  for (int s0 = 0; s0 < CHROWS; s0 += 8) {
    ushort4 ld = *(const ushort4*)(src + base + (size_t)(s0 + lrow) * D_MODEL + lcol);
    float f0 = h2f(ld.x), f1 = h2f(ld.y), f2 = h2f(ld.z), f3 = h2f(ld.w);
    __syncthreads();
    if (isV) { vv[lrow][lcol] = f0; vv[lrow][lcol+1] = f1; vv[lrow][lcol+2] = f2; vv[lrow][lcol+3] = f3; }
    else     { pk[lrow][lcol] = f0; pk[lrow][lcol+1] = f1; pk[lrow][lcol+2] = f2; pk[lrow][lcol+3] = f3; }
    __syncthreads();
#pragma unroll
    for (int ss = 0; ss < 8; ++ss) {
      float4 a  = *(const float4*)&pk[ss][dkb];
      float4 bb = *(const float4*)&vv[ss][deb];
      acc[0][0] += a.x * bb.x; acc[0][1] += a.x * bb.y; acc[0][2] += a.x * bb.z; acc[0][3] += a.x * bb.w;
      acc[1][0] += a.y * bb.x; acc[1][1] += a.y * bb.y; acc[1][2] += a.y * bb.z; acc[1][3] += a.y * bb.w;
      acc[2][0] += a.z * bb.x; acc[2][1] += a.z * bb.y; acc[2][2] += a.z * bb.z; acc[2][3] += a.z * bb.w;
      acc[3][0] += a.w * bb.x; acc[3][1] += a.w * bb.y; acc[3][2] += a.w * bb.z; acc[3][3] += a.w * bb.w;
    }
    if (t < 64) {
#pragma unroll
      for (int ss = 0; ss < 8; ++ss) zacc += pk[ss][t];
    }
  }
  float* Pb = P + ((size_t)c * 64 + bh) * PSTRIDE;
#pragma unroll
  for (int i = 0; i < 4; ++i) {
    float4 o; o.x = acc[i][0]; o.y = acc[i][1]; o.z = acc[i][2]; o.w = acc[i][3];
    *(float4*)(Pb + (size_t)(dkb + i) * DH + deb) = o;
  }
  if (t < 64) Pb[4096 + t] = zacc;
}

// ---------------- stage 2: reduce partials over chunks ---------------------
__global__ __launch_bounds__(256) void kvz_reduce(const float* __restrict__ P,
                                                  float* __restrict__ KV,
                                                  float* __restrict__ Z) {
  int bh = blockIdx.x;
  int t = threadIdx.x;
  for (int i = t; i < PSTRIDE; i += 256) {
    float s = 0.f;
#pragma unroll
    for (int c = 0; c < KVCH; ++c)
      s += P[((size_t)c * 64 + bh) * PSTRIDE + i];
    if (i < 4096) KV[(size_t)bh * 4096 + i] = s;
    else          Z[(size_t)bh * 64 + (i - 4096)] = s;
  }
}

// ---------------- attn (fp16 phiq in) -> fp16 ------------------------------
__global__ __launch_bounds__(256) void attn_kernel(const unsigned short* __restrict__ PQ,
                                                   const float* __restrict__ KVm,
                                                   const float* __restrict__ Z,
                                                   unsigned short* __restrict__ O) {
  int s0 = blockIdx.x << 6;
  int h = blockIdx.y, b = blockIdx.z;
  __shared__ float Pqt[64][64];
  __shared__ float Kv[64][64];
  __shared__ float den[64];
  __shared__ float zsh[64];
  int t = threadIdx.x;
  size_t qbase  = ((size_t)b * SEQ + s0) * D_MODEL + h * DH;
  size_t kvbase = (size_t)(b * NHEADS + h) * (DH * DH);
  int r0 = t >> 4;
  int c4 = (t & 15) << 2;
#pragma unroll
  for (int rr = 0; rr < 4; ++rr) {
    int row = r0 + (rr << 4);
    *(float4*)&Kv[row][c4] = *(const float4*)(KVm + kvbase + (size_t)row * DH + c4);
    ushort4 q = *(const ushort4*)(PQ + qbase + (size_t)row * D_MODEL + c4);
    Pqt[c4 + 0][row] = h2f(q.x);
    Pqt[c4 + 1][row] = h2f(q.y);
    Pqt[c4 + 2][row] = h2f(q.z);
    Pqt[c4 + 3][row] = h2f(q.w);
  }
  if (t < 16) *(float4*)&zsh[t << 2] = *(const float4*)(Z + (size_t)(b * NHEADS + h) * DH + (t << 2));
  __syncthreads();
  if (t < 64) {
    float d_ = 1e-6f;
#pragma unroll
    for (int dd = 0; dd < 64; ++dd) d_ += Pqt[dd][t] * zsh[dd];
    den[t] = d_;
  }
  __syncthreads();
  int tokb = (t >> 4) << 2, eb = (t & 15) << 2;
  float acc[4][4] = {};
#pragma unroll 8
  for (int dd = 0; dd < 64; ++dd) {
    float4 a  = *(const float4*)&Pqt[dd][tokb];
    float4 bb = *(const float4*)&Kv[dd][eb];
    acc[0][0] += a.x * bb.x; acc[0][1] += a.x * bb.y; acc[0][2] += a.x * bb.z; acc[0][3] += a.x * bb.w;
    acc[1][0] += a.y * bb.x; acc[1][1] += a.y * bb.y; acc[1][2] += a.y * bb.z; acc[1][3] += a.y * bb.w;
    acc[2][0] += a.z * bb.x; acc[2][1] += a.z * bb.y; acc[2][2] += a.z * bb.z; acc[2][3] += a.z * bb.w;
    acc[3][0] += a.w * bb.x; acc[3][1] += a.w * bb.y; acc[3][2] += a.w * bb.z; acc[3][3] += a.w * bb.w;
  }
#pragma unroll
  for (int i = 0; i < 4; ++i) {
    float dv = den[tokb + i];
    ushort4 hv;
    hv.x = f2h(acc[i][0] / dv);
    hv.y = f2h(acc[i][1] / dv);
    hv.z = f2h(acc[i][2] / dv);
    hv.w = f2h(acc[i][3] / dv);
    size_t oidx = ((size_t)b * SEQ + s0 + tokb + i) * D_MODEL + h * DH + eb;
    *(ushort4*)(O + oidx) = hv;
  }
}

extern "C" void kernel_launch(void* const* d_in, const int* in_sizes, int n_in,
                              void* d_out, int out_size, void* d_ws, size_t ws_size,
                              hipStream_t stream) {
  const float* x    = (const float*)d_in[0];
  const float* ln1g = (const float*)d_in[1];
  const float* ln1b = (const float*)d_in[2];
  const float* wq   = (const float*)d_in[3];
  const float* wk   = (const float*)d_in[4];
  const float* wv   = (const float*)d_in[5];
  const float* wo   = (const float*)d_in[6];
  const float* ln2g = (const float*)d_in[7];
  const float* ln2b = (const float*)d_in[8];
  const float* w1   = (const float*)d_in[9];
  const float* w2   = (const float*)d_in[10];
  float* out = (float*)d_out;
  char* ws = (char*)d_ws;

  const size_t MB = 1024 * 1024;
  unsigned short* xn   = (unsigned short*)(ws);
  unsigned short* qkv  = (unsigned short*)(ws + 32 * MB);  // phiq|phik|vbuf fp16
  unsigned short* phiq = qkv;
  unsigned short* phik = qkv + (size_t)NTOK * D_MODEL;
  unsigned short* vbuf = qkv + 2 * (size_t)NTOK * D_MODEL;
  unsigned short* ffn  = (unsigned short*)(ws + 32 * MB);  // overlays qkv slab
  unsigned short* w1T  = (unsigned short*)(ws + 96 * MB);
  unsigned short* w2T  = (unsigned short*)(ws + 104 * MB);
  unsigned short* woT  = (unsigned short*)(ws + 128 * MB);

  // d_out as scratch until wo-GEMM writes it
  unsigned short* wqkvT = (unsigned short*)d_out;          // [3072,1024] fp16
  float* kvP = (float*)((char*)d_out + 6 * MB);
  float* kv  = (float*)((char*)d_out + 24 * MB);
  float* z   = (float*)((char*)d_out + 25 * MB);

  dim3 blk(256);

  // wq/wk/wv -> wqkvT slabs, wo -> woT, one batched launch
  convT4<<<dim3(D_MODEL / 64, D_MODEL / 64, 4), blk, 0, stream>>>(
      wq, wk, wv, wo, wqkvT, woT);

  ln_kernel<<<NTOK, blk, 0, stream>>>(x, ln1g, ln1b, xn);

  // fused qkv: C[8192,3072] -> phi(q),phi(k) | v, fp16 slabs. B=6MB -> n-band
  dim3 gQKV(3 * D_MODEL / 128, NTOK / 128);
  mfma_gemm<4, 64, 1><<<gQKV, blk, 0, stream>>>(xn, wqkvT, qkv, nullptr, 3 * D_MODEL, D_MODEL);

  kvz_partial<<<dim3(KVCH, BATCH * NHEADS), blk, 0, stream>>>(phik, vbuf, kvP);
  kvz_reduce<<<BATCH * NHEADS, blk, 0, stream>>>(kvP, kv, z);

  attn_kernel<<<dim3(SEQ / 64, NHEADS, BATCH), blk, 0, stream>>>(phiq, kv, z, xn);

  convT<<<dim3(DFF / 64, D_MODEL / 64), blk, 0, stream>>>(w1, w1T, D_MODEL, DFF);
  convT<<<dim3(D_MODEL / 64, DFF / 64), blk, 0, stream>>>(w2, w2T, DFF, D_MODEL);

  dim3 gD(D_MODEL / 128, NTOK / 128);
  // x1 = x + attn@wo -> out.  B=2MB fits L2 -> m-band; grid-starved -> BK=128
  mfma_gemm<2, 128, 0><<<gD, blk, 0, stream>>>(xn, woT, out, x, D_MODEL, D_MODEL);

  ln_kernel<<<NTOK, blk, 0, stream>>>(out, ln2g, ln2b, xn);

  // ffn = gelu_lut(h @ w1).  B=8MB -> n-band (1MB/XCD resident)
  dim3 gF(DFF / 128, NTOK / 128);
  mfma_gemm<3, 64, 1><<<gF, blk, 0, stream>>>(xn, w1T, ffn, nullptr, DFF, D_MODEL);

  // out += ffn @ w2.  grid-starved, K=4096 -> BK=128; m-band
  mfma_gemm<2, 128, 0><<<gD, blk, 0, stream>>>(ffn, w2T, out, out, D_MODEL, DFF);
}

// Round 12
// 458.376 us; speedup vs baseline: 1.0761x; 1.0761x over previous
//
#include <hip/hip_runtime.h>
#include <cstdint>
#include <cstddef>

// PiFormerBlock, MFMA fp16 version, round 12: union of per-kernel winners.
//   x = x + linattn(LN1(x)) @ wo ;  x = x + gelu_lut(LN2(x) @ w1) @ w2
//  - qkv/w1: BK=64, (r&7) swizzle (0 conflicts r5-r8), m-band XCD swizzle.
//  - wo/w2 : BK=128, frow=(r^(r>>3))&7 (r9 fixed the 2^23 conflicts), m-band.
//  - No n-band (r11: each XCD streams all of A -> 245MB fetch, w1 +10us).
//  - No double-buffer (r10: __syncthreads drains the prefetch; m99 redux).
//  - convT4 batching kept (4x 1024x1024 weight transposes in one launch).
//
// ws layout (bytes):
//   0      xn    [8192x1024] fp16 (16MB)  (reused as attn out)
//   32MB   phiq  fp16 (16MB) \
//   48MB   phik  fp16 (16MB)  >-- contiguous qkv slab; later overlaid by
//   64MB   vbuf  fp16 (16MB) /    ffn fp16 [8192x4096] (64MB @ 32MB)
//   96MB   w1T   fp16 (8MB) | 104MB w2T fp16 (8MB) | 128MB woT fp16 (2MB)
// d_out scratch (dead before wo-GEMM writes it):
//   0MB wqkvT (6MB) | 6MB kv partials (17.04MB) | 24MB kv (1MB) | 25MB z

#define D_MODEL 1024
#define SEQ     2048
#define BATCH   4
#define NTOK    8192
#define NHEADS  16
#define DH      64
#define DFF     4096
#define KVCH    16
#define CHROWS  (SEQ / KVCH)
#define PSTRIDE 4160

typedef _Float16 half8 __attribute__((ext_vector_type(8)));
typedef float f32x4 __attribute__((ext_vector_type(4)));

__device__ __forceinline__ unsigned short f2h(float x) {
  _Float16 h = (_Float16)x;
  union { _Float16 h; unsigned short u; } c; c.h = h; return c.u;
}
__device__ __forceinline__ float h2f(unsigned short u) {
  union { unsigned short u; _Float16 h; } c; c.u = u; return (float)c.h;
}

__device__ __forceinline__ float phi_act(float x) {
  return x > 0.f ? x + 1.f : expf(x);
}

__device__ __forceinline__ float gelu_exact(float v) {
  float c = 0.7978845608028654f;
  float t = tanhf(c * (v + 0.044715f * v * v * v));
  return 0.5f * v * (1.f + t);
}

// per-BK row->segment swizzle (both measured-optimal):
//   BK=64 : r&7          (0 conflicts, rounds 5-8)
//   BK=128: (r^(r>>3))&7 (round 9: fixes the 4cyc/b128 penalty of r&7)
template <int BK>
__device__ __forceinline__ int fr(int r) {
  return (BK == 128) ? ((r ^ (r >> 3)) & 7) : (r & 7);
}

__device__ __forceinline__ void gl_lds16(const void* g, void* l) {
  __builtin_amdgcn_global_load_lds(
      (const __attribute__((address_space(1))) unsigned int*)g,
      (__attribute__((address_space(3))) unsigned int*)l, 16, 0, 0);
}

// ------- batched transpose-convert: 4x [1024,1024] fp32 -> fp16 [N,K]^T -----
__global__ __launch_bounds__(256) void convT4(const float* __restrict__ W0,
                                              const float* __restrict__ W1,
                                              const float* __restrict__ W2,
                                              const float* __restrict__ W3,
                                              unsigned short* __restrict__ D0,
                                              unsigned short* __restrict__ D3) {
  __shared__ float tile[64][65];
  int zz = blockIdx.z;
  const float* W = zz == 0 ? W0 : zz == 1 ? W1 : zz == 2 ? W2 : W3;
  unsigned short* WT = zz < 3 ? (D0 + (size_t)zz * D_MODEL * D_MODEL) : D3;
  int kb = blockIdx.y << 6, nb = blockIdx.x << 6;
  int t = threadIdx.x;
  int rr = t >> 4, cc = (t & 15) << 2;
#pragma unroll
  for (int i = 0; i < 4; ++i) {
    int r = rr + (i << 4);
    float4 v = *(const float4*)(W + (size_t)(kb + r) * D_MODEL + nb + cc);
    tile[r][cc] = v.x; tile[r][cc + 1] = v.y; tile[r][cc + 2] = v.z; tile[r][cc + 3] = v.w;
  }
  __syncthreads();
#pragma unroll
  for (int i = 0; i < 4; ++i) {
    int n = rr + (i << 4);
    ushort4 o;
    o.x = f2h(tile[cc + 0][n]); o.y = f2h(tile[cc + 1][n]);
    o.z = f2h(tile[cc + 2][n]); o.w = f2h(tile[cc + 3][n]);
    *(ushort4*)(WT + (size_t)(nb + n) * D_MODEL + kb + cc) = o;
  }
}

// ---------------- transpose-convert: W fp32 [K,N] -> WT fp16 [N,K] ----------
__global__ __launch_bounds__(256) void convT(const float* __restrict__ W,
                                             unsigned short* __restrict__ WT,
                                             int K, int N) {
  __shared__ float tile[64][65];
  int kb = blockIdx.y << 6, nb = blockIdx.x << 6;
  int t = threadIdx.x;
  int rr = t >> 4, cc = (t & 15) << 2;
#pragma unroll
  for (int i = 0; i < 4; ++i) {
    int r = rr + (i << 4);
    float4 v = *(const float4*)(W + (size_t)(kb + r) * N + nb + cc);
    tile[r][cc] = v.x; tile[r][cc + 1] = v.y; tile[r][cc + 2] = v.z; tile[r][cc + 3] = v.w;
  }
  __syncthreads();
#pragma unroll
  for (int i = 0; i < 4; ++i) {
    int n = rr + (i << 4);
    ushort4 o;
    o.x = f2h(tile[cc + 0][n]); o.y = f2h(tile[cc + 1][n]);
    o.z = f2h(tile[cc + 2][n]); o.w = f2h(tile[cc + 3][n]);
    *(ushort4*)(WT + (size_t)(nb + n) * K + kb + cc) = o;
  }
}

// ---------------- LayerNorm -> fp16 ----------------------------------------
__global__ __launch_bounds__(256) void ln_kernel(const float* __restrict__ X,
                                                 const float* __restrict__ g,
                                                 const float* __restrict__ b,
                                                 unsigned short* __restrict__ Y) {
  int tok = blockIdx.x;
  int t = threadIdx.x;
  const float4* xr = (const float4*)(X + (size_t)tok * D_MODEL);
  float4 v = xr[t];
  float s  = v.x + v.y + v.z + v.w;
  float s2 = v.x * v.x + v.y * v.y + v.z * v.z + v.w * v.w;
#pragma unroll
  for (int o = 32; o > 0; o >>= 1) {
    s  += __shfl_down(s, o);
    s2 += __shfl_down(s2, o);
  }
  __shared__ float red[8];
  __shared__ float mu_s, rs_s;
  int wid = t >> 6;
  if ((t & 63) == 0) { red[wid] = s; red[wid + 4] = s2; }
  __syncthreads();
  if (t == 0) {
    float ts  = red[0] + red[1] + red[2] + red[3];
    float ts2 = red[4] + red[5] + red[6] + red[7];
    float mu  = ts * (1.f / D_MODEL);
    float var = ts2 * (1.f / D_MODEL) - mu * mu;
    mu_s = mu;
    rs_s = rsqrtf(var + 1e-5f);
  }
  __syncthreads();
  float mu = mu_s, rs = rs_s;
  float4 gv = ((const float4*)g)[t];
  float4 bv = ((const float4*)b)[t];
  ushort4 hv;
  hv.x = f2h((v.x - mu) * rs * gv.x + bv.x);
  hv.y = f2h((v.y - mu) * rs * gv.y + bv.y);
  hv.z = f2h((v.z - mu) * rs * gv.z + bv.z);
  hv.w = f2h((v.w - mu) * rs * gv.w + bv.w);
  ((ushort4*)(Y + (size_t)tok * D_MODEL))[t] = hv;
}

// ---------------- MFMA GEMM: C[M,N] = A[M,K] @ BT[N,K]^T (fp16 in) ---------
// EP: 0 fp32 | 2 +R fp32 | 3 gelu-LUT fp16 | 4 fused qkv (phi on q/k) fp16
// BK: K-chunk per barrier (64 -> 32KB LDS 4blk/CU, 128 -> 64KB LDS 2blk/CU)
template <int EP, int BK>
__global__ __launch_bounds__(256, (BK == 64) ? 4 : 2) void mfma_gemm(
    const unsigned short* __restrict__ A,
    const unsigned short* __restrict__ BT,
    void* Cv, const float* R, int N, int K) {
  constexpr int SEGS = BK / 8;     // 16B segments per row
  constexpr int RPC  = 64 / SEGS;  // rows covered by one gl_lds16 call
  constexpr int NJ   = 32 / RPC;   // calls per wave per tile (32 rows/wave)
  __shared__ unsigned short smem[2 * 128 * BK];
  __shared__ float gtab[EP == 3 ? 256 : 1];
  unsigned short* sA = smem;
  unsigned short* sB = smem + 128 * BK;

  int t = threadIdx.x;
  if (EP == 3) gtab[t & 255] = gelu_exact((float)((t & 255) - 128) * 0.1f);

  // XCD-aware m-band swizzle: XCD owns a contiguous band of m rows, walks n
  // fastest (A-tile stays in that XCD's L2; B re-streams -- measured cheaper
  // than n-band for every GEMM here, r10 vs r11).
  int bm, bn;
  {
    int L = blockIdx.y * gridDim.x + blockIdx.x;
    if ((gridDim.y & 7) == 0) {
      int xcd = L & 7, wi = L >> 3;
      int mPerX = gridDim.y >> 3;
      bm = xcd * mPerX + wi / gridDim.x;
      bn = wi % gridDim.x;
    } else {
      bn = blockIdx.x; bm = blockIdx.y;
    }
  }

  int w = t >> 6, l = t & 63;
  int lrow = l / SEGS;             // row within call group
  int lseg = l & (SEGS - 1);       // 16B segment within row
  int m0 = bm << 7;
  int n0 = bn << 7;
  size_t strideB = (size_t)K * 2;

  const char* gA[NJ]; const char* gB[NJ];
  int ldsOff[NJ];
#pragma unroll
  for (int j = 0; j < NJ; ++j) {
    int row = (w << 5) + j * RPC + lrow;
    int gso = (lseg ^ fr<BK>(row)) << 4;   // swizzled segment offset (bytes)
    gA[j] = (const char*)A + (size_t)(m0 + row) * strideB + gso;
    gB[j] = (const char*)BT + (size_t)(n0 + row) * strideB + gso;
    ldsOff[j] = ((w << 5) + j * RPC) * BK;  // shorts
  }

  int wm = w >> 1, wn = w & 1;
  int m16 = l & 15, qd = l >> 4;

  f32x4 acc[4][4];
#pragma unroll
  for (int i = 0; i < 4; ++i)
#pragma unroll
    for (int j = 0; j < 4; ++j) acc[i][j] = (f32x4){0.f, 0.f, 0.f, 0.f};

  for (int k0 = 0; k0 < K; k0 += BK) {
    size_t kb = (size_t)k0 * 2;
#pragma unroll
    for (int j = 0; j < NJ; ++j) {
      gl_lds16(gA[j] + kb, sA + ldsOff[j]);
      gl_lds16(gB[j] + kb, sB + ldsOff[j]);
    }
    __syncthreads();
#pragma unroll
    for (int kk = 0; kk < BK / 32; ++kk) {
      int ksb = (kk << 2) + qd;
      half8 af[4], bf[4];
#pragma unroll
      for (int mt = 0; mt < 4; ++mt) {
        int r = (wm << 6) + (mt << 4) + m16;
        int slot = ksb ^ fr<BK>(r);
        af[mt] = *(const half8*)(sA + r * BK + (slot << 3));
      }
#pragma unroll
      for (int nt = 0; nt < 4; ++nt) {
        int r = (wn << 6) + (nt << 4) + m16;
        int slot = ksb ^ fr<BK>(r);
        bf[nt] = *(const half8*)(sB + r * BK + (slot << 3));
      }
#pragma unroll
      for (int mt = 0; mt < 4; ++mt)
#pragma unroll
        for (int nt = 0; nt < 4; ++nt)
          acc[mt][nt] = __builtin_amdgcn_mfma_f32_16x16x32_f16(af[mt], bf[nt], acc[mt][nt], 0, 0, 0);
    }
    __syncthreads();
  }

  // EP=4: destination slab by column block (n0 is 128-aligned, slabs 1024-wide)
  int sel = n0 >> 10;                       // 0=q 1=k 2=v
  size_t slab = (size_t)sel * ((size_t)NTOK * D_MODEL);
  int colL = (n0 & 1023) + (wn << 6) + m16; // local col within slab

  int colBase = n0 + (wn << 6) + m16;
#pragma unroll
  for (int mt = 0; mt < 4; ++mt) {
    int rBase = m0 + (wm << 6) + (mt << 4) + (qd << 2);
#pragma unroll
    for (int nt = 0; nt < 4; ++nt) {
      int col = colBase + (nt << 4);
#pragma unroll
      for (int i = 0; i < 4; ++i) {
        float v = acc[mt][nt][i];
        if (EP == 4) {
          if (sel < 2) v = phi_act(v);
          size_t idx = slab + (size_t)(rBase + i) * D_MODEL + colL + (nt << 4);
          ((unsigned short*)Cv)[idx] = f2h(v);
        } else {
          size_t idx = (size_t)(rBase + i) * N + col;
          if (EP == 2)      ((float*)Cv)[idx] = R[idx] + v;
          else if (EP == 3) {
            float r = rintf(v / 0.1f);
            int iq = (int)r + 128;
            iq = iq < 0 ? 0 : (iq > 255 ? 255 : iq);
            ((unsigned short*)Cv)[idx] = f2h(gtab[iq]);
          } else          ((float*)Cv)[idx] = v;
        }
      }
    }
  }
}

// ---------------- stage 1: partial kv/z over an S-chunk (fp16 in) ----------
__global__ __launch_bounds__(256) void kvz_partial(const unsigned short* __restrict__ PK,
                                                   const unsigned short* __restrict__ V,
                                                   float* __restrict__ P) {
  int c = blockIdx.x, bh = blockIdx.y;
  int b = bh >> 4, h = bh & 15;
  __shared__ float pk[8][64];
  __shared__ float vv[8][64];
  int t = threadIdx.x;
  const size_t base = ((size_t)b * SEQ + (size_t)c * CHROWS) * D_MODEL + h * DH;
  int u = t & 127;
  int lrow = u >> 4;
  int lcol = (u & 15) << 2;
  bool isV = (t >= 128);
  const unsigned short* src = isV ? V : PK;
  int dkb = (t >> 4) << 2;
  int deb = (t & 15) << 2;
  float acc[4][4] = {};
  float zacc = 0.f;
  for (int s0 = 0; s0 < CHROWS; s0 += 8) {
    ushort4 ld = *(const ushort4*)(src + base + (size_t)(s0 + lrow) * D_MODEL + lcol);
    float f0 = h2f(ld.x), f1 = h2f(ld.y), f2 = h2f(ld.z), f3 = h2f(ld.w);
    __syncthreads();
    if (isV) { vv[lrow][lcol] = f0; vv[lrow][lcol+1] = f1; vv[lrow][lcol+2] = f2; vv[lrow][lcol+3] = f3; }
    else     { pk[lrow][lcol] = f0; pk[lrow][lcol+1] = f1; pk[lrow][lcol+2] = f2; pk[lrow][lcol+3] = f3; }
    __syncthreads();
#pragma unroll
    for (int ss = 0; ss < 8; ++ss) {
      float4 a  = *(const float4*)&pk[ss][dkb];
      float4 bb = *(const float4*)&vv[ss][deb];
      acc[0][0] += a.x * bb.x; acc[0][1] += a.x * bb.y; acc[0][2] += a.x * bb.z; acc[0][3] += a.x * bb.w;
      acc[1][0] += a.y * bb.x; acc[1][1] += a.y * bb.y; acc[1][2] += a.y * bb.z; acc[1][3] += a.y * bb.w;
      acc[2][0] += a.z * bb.x; acc[2][1] += a.z * bb.y; acc[2][2] += a.z * bb.z; acc[2][3] += a.z * bb.w;
      acc[3][0] += a.w * bb.x; acc[3][1] += a.w * bb.y; acc[3][2] += a.w * bb.z; acc[3][3] += a.w * bb.w;
    }
    if (t < 64) {
#pragma unroll
      for (int ss = 0; ss < 8; ++ss) zacc += pk[ss][t];
    }
  }
  float* Pb = P + ((size_t)c * 64 + bh) * PSTRIDE;
#pragma unroll
  for (int i = 0; i < 4; ++i) {
    float4 o; o.x = acc[i][0]; o.y = acc[i][1]; o.z = acc[i][2]; o.w = acc[i][3];
    *(float4*)(Pb + (size_t)(dkb + i) * DH + deb) = o;
  }
  if (t < 64) Pb[4096 + t] = zacc;
}

// ---------------- stage 2: reduce partials over chunks ---------------------
__global__ __launch_bounds__(256) void kvz_reduce(const float* __restrict__ P,
                                                  float* __restrict__ KV,
                                                  float* __restrict__ Z) {
  int bh = blockIdx.x;
  int t = threadIdx.x;
  for (int i = t; i < PSTRIDE; i += 256) {
    float s = 0.f;
#pragma unroll
    for (int c = 0; c < KVCH; ++c)
      s += P[((size_t)c * 64 + bh) * PSTRIDE + i];
    if (i < 4096) KV[(size_t)bh * 4096 + i] = s;
    else          Z[(size_t)bh * 64 + (i - 4096)] = s;
  }
}

// ---------------- attn (fp16 phiq in) -> fp16 ------------------------------
__global__ __launch_bounds__(256) void attn_kernel(const unsigned short* __restrict__ PQ,
                                                   const float* __restrict__ KVm,
                                                   const float* __restrict__ Z,
                                                   unsigned short* __restrict__ O) {
  int s0 = blockIdx.x << 6;
  int h = blockIdx.y, b = blockIdx.z;
  __shared__ float Pqt[64][64];
  __shared__ float Kv[64][64];
  __shared__ float den[64];
  __shared__ float zsh[64];
  int t = threadIdx.x;
  size_t qbase  = ((size_t)b * SEQ + s0) * D_MODEL + h * DH;
  size_t kvbase = (size_t)(b * NHEADS + h) * (DH * DH);
  int r0 = t >> 4;
  int c4 = (t & 15) << 2;
#pragma unroll
  for (int rr = 0; rr < 4; ++rr) {
    int row = r0 + (rr << 4);
    *(float4*)&Kv[row][c4] = *(const float4*)(KVm + kvbase + (size_t)row * DH + c4);
    ushort4 q = *(const ushort4*)(PQ + qbase + (size_t)row * D_MODEL + c4);
    Pqt[c4 + 0][row] = h2f(q.x);
    Pqt[c4 + 1][row] = h2f(q.y);
    Pqt[c4 + 2][row] = h2f(q.z);
    Pqt[c4 + 3][row] = h2f(q.w);
  }
  if (t < 16) *(float4*)&zsh[t << 2] = *(const float4*)(Z + (size_t)(b * NHEADS + h) * DH + (t << 2));
  __syncthreads();
  if (t < 64) {
    float d_ = 1e-6f;
#pragma unroll
    for (int dd = 0; dd < 64; ++dd) d_ += Pqt[dd][t] * zsh[dd];
    den[t] = d_;
  }
  __syncthreads();
  int tokb = (t >> 4) << 2, eb = (t & 15) << 2;
  float acc[4][4] = {};
#pragma unroll 8
  for (int dd = 0; dd < 64; ++dd) {
    float4 a  = *(const float4*)&Pqt[dd][tokb];
    float4 bb = *(const float4*)&Kv[dd][eb];
    acc[0][0] += a.x * bb.x; acc[0][1] += a.x * bb.y; acc[0][2] += a.x * bb.z; acc[0][3] += a.x * bb.w;
    acc[1][0] += a.y * bb.x; acc[1][1] += a.y * bb.y; acc[1][2] += a.y * bb.z; acc[1][3] += a.y * bb.w;
    acc[2][0] += a.z * bb.x; acc[2][1] += a.z * bb.y; acc[2][2] += a.z * bb.z; acc[2][3] += a.z * bb.w;
    acc[3][0] += a.w * bb.x; acc[3][1] += a.w * bb.y; acc[3][2] += a.w * bb.z; acc[3][3] += a.w * bb.w;
  }
#pragma unroll
  for (int i = 0; i < 4; ++i) {
    float dv = den[tokb + i];
    ushort4 hv;
    hv.x = f2h(acc[i][0] / dv);
    hv.y = f2h(acc[i][1] / dv);
    hv.z = f2h(acc[i][2] / dv);
    hv.w = f2h(acc[i][3] / dv);
    size_t oidx = ((size_t)b * SEQ + s0 + tokb + i) * D_MODEL + h * DH + eb;
    *(ushort4*)(O + oidx) = hv;
  }
}

extern "C" void kernel_launch(void* const* d_in, const int* in_sizes, int n_in,
                              void* d_out, int out_size, void* d_ws, size_t ws_size,
                              hipStream_t stream) {
  const float* x    = (const float*)d_in[0];
  const float* ln1g = (const float*)d_in[1];
  const float* ln1b = (const float*)d_in[2];
  const float* wq   = (const float*)d_in[3];
  const float* wk   = (const float*)d_in[4];
  const float* wv   = (const float*)d_in[5];
  const float* wo   = (const float*)d_in[6];
  const float* ln2g = (const float*)d_in[7];
  const float* ln2b = (const float*)d_in[8];
  const float* w1   = (const float*)d_in[9];
  const float* w2   = (const float*)d_in[10];
  float* out = (float*)d_out;
  char* ws = (char*)d_ws;

  const size_t MB = 1024 * 1024;
  unsigned short* xn   = (unsigned short*)(ws);
  unsigned short* qkv  = (unsigned short*)(ws + 32 * MB);  // phiq|phik|vbuf fp16
  unsigned short* phiq = qkv;
  unsigned short* phik = qkv + (size_t)NTOK * D_MODEL;
  unsigned short* vbuf = qkv + 2 * (size_t)NTOK * D_MODEL;
  unsigned short* ffn  = (unsigned short*)(ws + 32 * MB);  // overlays qkv slab
  unsigned short* w1T  = (unsigned short*)(ws + 96 * MB);
  unsigned short* w2T  = (unsigned short*)(ws + 104 * MB);
  unsigned short* woT  = (unsigned short*)(ws + 128 * MB);

  // d_out as scratch until wo-GEMM writes it
  unsigned short* wqkvT = (unsigned short*)d_out;          // [3072,1024] fp16
  float* kvP = (float*)((char*)d_out + 6 * MB);
  float* kv  = (float*)((char*)d_out + 24 * MB);
  float* z   = (float*)((char*)d_out + 25 * MB);

  dim3 blk(256);

  // wq/wk/wv -> wqkvT slabs, wo -> woT, one batched launch
  convT4<<<dim3(D_MODEL / 64, D_MODEL / 64, 4), blk, 0, stream>>>(
      wq, wk, wv, wo, wqkvT, woT);

  ln_kernel<<<NTOK, blk, 0, stream>>>(x, ln1g, ln1b, xn);

  // fused qkv: C[8192,3072] -> phi(q),phi(k) | v, fp16 slabs
  dim3 gQKV(3 * D_MODEL / 128, NTOK / 128);
  mfma_gemm<4, 64><<<gQKV, blk, 0, stream>>>(xn, wqkvT, qkv, nullptr, 3 * D_MODEL, D_MODEL);

  kvz_partial<<<dim3(KVCH, BATCH * NHEADS), blk, 0, stream>>>(phik, vbuf, kvP);
  kvz_reduce<<<BATCH * NHEADS, blk, 0, stream>>>(kvP, kv, z);

  attn_kernel<<<dim3(SEQ / 64, NHEADS, BATCH), blk, 0, stream>>>(phiq, kv, z, xn);

  convT<<<dim3(DFF / 64, D_MODEL / 64), blk, 0, stream>>>(w1, w1T, D_MODEL, DFF);
  convT<<<dim3(D_MODEL / 64, DFF / 64), blk, 0, stream>>>(w2, w2T, DFF, D_MODEL);

  dim3 gD(D_MODEL / 128, NTOK / 128);
  // x1 = x + attn@wo -> out  (grid-starved: BK=128 + frow)
  mfma_gemm<2, 128><<<gD, blk, 0, stream>>>(xn, woT, out, x, D_MODEL, D_MODEL);

  ln_kernel<<<NTOK, blk, 0, stream>>>(out, ln2g, ln2b, xn);

  // ffn = gelu_lut(h @ w1)  (BK=64 + (r&7), m-band)
  dim3 gF(DFF / 128, NTOK / 128);
  mfma_gemm<3, 64><<<gF, blk, 0, stream>>>(xn, w1T, ffn, nullptr, DFF, D_MODEL);

  // out += ffn @ w2  (grid-starved, K=4096: BK=128 + frow)
  mfma_gemm<2, 128><<<gD, blk, 0, stream>>>(ffn, w2T, out, out, D_MODEL, DFF);
}